// Round 4
// baseline (226.806 us; speedup 1.0000x reference)
//
#include <hip/hip_runtime.h>

// Problem constants (from reference): S=7, B=2, C=20, N=30, batch=16384
#define NCH 30
#define RANK_LIMIT 49          // S*S
#define L_COORD 5.0f
#define L_NOOBJ 0.5f

// Exact-cover streaming geometry: 802816 rows * 30 floats / 4 = 6,021,120
// float4 per array = 4704 blocks * 256 threads * unroll 5 exactly.
#define NF4 6021120
#define NB 4704
#define UNROLL 5
#define STRIDE (NB * 256)          // 1,204,224

// ws layout: [0, NB) floats = noobj per-block partials; gates at +64 KB:
// float2-ish per row, stored as float[2*row] = t4, float[2*row+1] = t9.
#define GATE_OFF_FLOATS 16384      // 64 KB / 4

// ---------------------------------------------------------------------------
// K1: stream TARGET as one contiguous float4 stream (m13 shape: exact cover,
// no bounds checks, 5 independent loads in flight, no LDS/barriers) and
// compact the per-row (t4, t9) into a 6.4 MB gate table.
// Decode: 60-float (2-row) group; pair=i/15, k=i%15.
//   k==1 -> even row ch4 = v.x   k==2 -> even row ch9 = v.y
//   k==8 -> odd  row ch4 = v.z   k==9 -> odd  row ch9 = v.w
// ---------------------------------------------------------------------------
__global__ __launch_bounds__(256) void gate_kernel(const float4* __restrict__ tv,
                                                   float* __restrict__ gate) {
    int gid = blockIdx.x * 256 + threadIdx.x;
    float4 v[UNROLL];
    #pragma unroll
    for (int u = 0; u < UNROLL; ++u)
        v[u] = tv[gid + u * STRIDE];
    #pragma unroll
    for (int u = 0; u < UNROLL; ++u) {
        int i = gid + u * STRIDE;
        int pair = i / 15;
        int k = i - pair * 15;
        int g = 4 * pair;          // float index of even row's t4 slot
        if (k == 1)      gate[g + 0] = v[u].x;
        else if (k == 2) gate[g + 1] = v[u].y;
        else if (k == 8) gate[g + 2] = v[u].z;
        else if (k == 9) gate[g + 3] = v[u].w;
    }
}

// ---------------------------------------------------------------------------
// K2: stream PRED as one contiguous float4 stream; gates (6.4 MB) come from
// L2/L3. Accumulate noobj sum; one partial per block (no atomics/memset).
// ---------------------------------------------------------------------------
__global__ __launch_bounds__(256) void noobj_kernel(const float4* __restrict__ pv,
                                                    const float* __restrict__ gate,
                                                    float* __restrict__ partials) {
    int gid = blockIdx.x * 256 + threadIdx.x;
    float4 v[UNROLL];
    #pragma unroll
    for (int u = 0; u < UNROLL; ++u)
        v[u] = pv[gid + u * STRIDE];

    float acc = 0.0f;
    #pragma unroll
    for (int u = 0; u < UNROLL; ++u) {
        int i = gid + u * STRIDE;
        int pair = i / 15;
        int k = i - pair * 15;
        int g = 4 * pair;
        if (k == 1) {
            float t4 = gate[g + 0];
            if (!(t4 > 0.0f)) { float d = v[u].x - t4; acc += d * d; }
        } else if (k == 2) {
            float t4 = gate[g + 0];
            if (!(t4 > 0.0f)) { float d = v[u].y - gate[g + 1]; acc += d * d; }
        } else if (k == 8) {
            float t4 = gate[g + 2];
            if (!(t4 > 0.0f)) { float d = v[u].z - t4; acc += d * d; }
        } else if (k == 9) {
            float t4 = gate[g + 2];
            if (!(t4 > 0.0f)) { float d = v[u].w - gate[g + 3]; acc += d * d; }
        }
    }

    #pragma unroll
    for (int off = 32; off > 0; off >>= 1)
        acc += __shfl_down(acc, off, 64);
    __shared__ float s[4];
    int lane = threadIdx.x & 63;
    int wid  = threadIdx.x >> 6;
    if (lane == 0) s[wid] = acc;
    __syncthreads();
    if (threadIdx.x == 0)
        partials[blockIdx.x] = s[0] + s[1] + s[2] + s[3];
}

// ---------------------------------------------------------------------------
// Per-row "selected" bbox loss — faithful port of the reference including its
// bugs: x2y2 built from the already-transformed xy; lambda_coord only on the
// x / sqrt(w) terms; selected loss sums l1+l2+l3+IoU; argmax keeps first max.
// ---------------------------------------------------------------------------
__device__ inline float sel_loss(const float* __restrict__ p,
                                 const float* __restrict__ t, int row) {
    const float invS = 1.0f / 7.0f;
    int b0 = row * NCH;
    float tot0 = 0.f, tot1 = 0.f, iou0 = 0.f, iou1 = 0.f;
    #pragma unroll
    for (int j = 0; j < 2; ++j) {
        int o = b0 + 5 * j;
        float px = p[o + 0], py = p[o + 1], pw = p[o + 2], ph = p[o + 3], pc = p[o + 4];
        float tx = t[o + 0], ty = t[o + 1], tw = t[o + 2], th = t[o + 3], tc = t[o + 4];
        float pxy0 = px * invS - 0.5f * pw;
        float pxy1 = py * invS - 0.5f * ph;
        float p2x  = pxy0 * invS + 0.5f * pw;
        float p2y  = pxy1 * invS + 0.5f * ph;
        float txy0 = tx * invS - 0.5f * tw;
        float txy1 = ty * invS - 0.5f * th;
        float t2x  = txy0 * invS + 0.5f * tw;
        float t2y  = txy1 * invS + 0.5f * th;
        float d0 = txy0 - pxy0, d1 = txy1 - pxy1;
        float l1 = L_COORD * d0 * d0 + d1 * d1;
        float s0 = sqrtf(t2x) - sqrtf(p2x);
        float s1 = sqrtf(t2y) - sqrtf(p2y);
        float l2 = L_COORD * s0 * s0 + s1 * s1;
        float dc = tc - pc;
        float l3 = dc * dc;
        float ltx = fmaxf(pxy0, txy0), lty = fmaxf(pxy1, txy1);
        float rbx = fminf(p2x, t2x),   rby = fminf(p2y, t2y);
        float wx  = fmaxf(rbx - ltx, 0.0f);
        float wy  = fmaxf(rby - lty, 0.0f);
        float inter  = wx * wy;
        float area_p = (p2x - pxy0) * (p2y - pxy1);
        float area_t = (t2x - txy0) * (t2y - txy1);
        float io = inter / (area_p + area_t - inter);
        float tt = l1 + l2 + l3 + io;
        if (j == 0) { iou0 = io; tot0 = tt; }
        else        { iou1 = io; tot1 = tt; }
    }
    return (iou1 > iou0) ? tot1 : tot0;   // argmax keeps FIRST max
}

// ---------------------------------------------------------------------------
// K3: ordered ballot-scan for the bbox loss + final combine. Single block;
// uniform early exit once 49 objects consumed (~1 chunk at 25% density).
// Also folds the NB noobj partials.
// ---------------------------------------------------------------------------
__global__ __launch_bounds__(256) void bbox_kernel(const float* __restrict__ p,
                                                   const float* __restrict__ t,
                                                   const float* __restrict__ partials,
                                                   float* __restrict__ out, int M) {
    __shared__ int   s_wcnt[4];
    __shared__ int   s_base;
    __shared__ float s_part[4];
    if (threadIdx.x == 0) s_base = 0;
    __syncthreads();

    float local = 0.0f;
    for (int start = 0; start < M; start += 256) {
        int row = start + (int)threadIdx.x;
        bool obj = false;
        if (row < M) obj = t[row * NCH + 4] > 0.0f;

        unsigned long long mask = __ballot(obj);
        int lane = threadIdx.x & 63;
        int wid  = threadIdx.x >> 6;
        if (lane == 0) s_wcnt[wid] = __popcll(mask);
        __syncthreads();

        int base = s_base;
        int off = 0;
        for (int w = 0; w < wid; ++w) off += s_wcnt[w];
        int rank = base + off + __popcll(mask & ((1ULL << lane) - 1ULL));
        if (obj && rank < RANK_LIMIT) local += sel_loss(p, t, row);
        __syncthreads();

        if (threadIdx.x == 0)
            s_base = base + s_wcnt[0] + s_wcnt[1] + s_wcnt[2] + s_wcnt[3];
        __syncthreads();
        if (s_base >= RANK_LIMIT) break;
    }

    for (int i = threadIdx.x; i < NB; i += 256)
        local += L_NOOBJ * partials[i];

    #pragma unroll
    for (int o = 32; o > 0; o >>= 1)
        local += __shfl_down(local, o, 64);
    int lane = threadIdx.x & 63;
    int wid  = threadIdx.x >> 6;
    if (lane == 0) s_part[wid] = local;
    __syncthreads();
    if (threadIdx.x == 0)
        out[0] = s_part[0] + s_part[1] + s_part[2] + s_part[3];
}

extern "C" void kernel_launch(void* const* d_in, const int* in_sizes, int n_in,
                              void* d_out, int out_size, void* d_ws, size_t ws_size,
                              hipStream_t stream) {
    const float* pred = (const float*)d_in[0];
    const float* targ = (const float*)d_in[1];
    float* out = (float*)d_out;
    float* partials = (float*)d_ws;                     // NB floats
    float* gate = (float*)d_ws + GATE_OFF_FLOATS;       // 6.4 MB (2 floats/row)

    int M = in_sizes[0] / NCH;                          // 802816 rows

    gate_kernel<<<NB, 256, 0, stream>>>((const float4*)targ, gate);
    noobj_kernel<<<NB, 256, 0, stream>>>((const float4*)pred, gate, partials);
    bbox_kernel<<<1, 256, 0, stream>>>(pred, targ, partials, out, M);
}

// Round 6
// 197.007 us; speedup vs baseline: 1.1513x; 1.1513x over previous
//
#include <hip/hip_runtime.h>

// Problem constants (from reference): S=7, B=2, C=20, N=30, batch=16384
#define NCH 30
#define RANK_LIMIT 49          // S*S
#define L_COORD 5.0f
#define L_NOOBJ 0.5f

// Exact-cover geometry: 802816 rows * 30 / 4 = 6,021,120 float4 per array.
// 5880 blocks * 256 threads * unroll 4 = 6,021,120 exactly.
#define NB 5880
#define UNROLL 4

// Native clang vector type — __builtin_nontemporal_load requires a plain
// scalar/vector pointee, not HIP's HIP_vector_type wrapper class.
typedef float vfloat4 __attribute__((ext_vector_type(4)));

// ---------------------------------------------------------------------------
// Fused noobj streamer (v5b). R1/R3/R4 all cap at ~2.0-2.7 TB/s effective
// read while the harness's 385MB poison fill writes at 6.8 TB/s -> theory:
// the read-allocate cache path is the cap (inputs half-L3-resident after the
// harness d2d restore; FETCH_SIZE ~110MB < 193MB). This version streams both
// arrays with NON-TEMPORAL float4 loads (global_load_dwordx4 nt), 8
// independent loads in flight per thread, no LDS/barrier in the stream.
//
// Channel decode (60-float / 15-float4 two-row groups, pair=i/15, k=i%15):
//   k==1: even-row ch4..7  -> t4 = vt.x (gate+term), p4 = vp.x
//   k==2: even-row ch8..11 -> t9 = vt.y, p9 = vp.y, gate t4 = lane(l-1) vt.x
//   k==8: odd-row  ch2..5  -> t4 = vt.z (gate+term), p4 = vp.z
//   k==9: odd-row  ch6..9  -> t9 = vt.w, p9 = vp.w, gate t4 = lane(l-1) vt.z
// Lanes hold consecutive i, so the k==2/k==9 gate is __shfl_up(.,1) of the
// neighbor's vector; lane 0 falls back to a (rare) scalar load.
// ---------------------------------------------------------------------------
__global__ __launch_bounds__(256) void noobj_kernel(const vfloat4* __restrict__ pv,
                                                    const vfloat4* __restrict__ tv,
                                                    const float* __restrict__ ts,
                                                    float* __restrict__ partials) {
    const int tid  = threadIdx.x;
    const int lane = tid & 63;
    const int base = blockIdx.x * (256 * UNROLL) + tid;

    vfloat4 vp[UNROLL], vt[UNROLL];
    // Issue all 8 non-temporal vector loads first — fully independent.
    #pragma unroll
    for (int u = 0; u < UNROLL; ++u) {
        int i = base + u * 256;
        vp[u] = __builtin_nontemporal_load(&pv[i]);
        vt[u] = __builtin_nontemporal_load(&tv[i]);
    }

    float acc = 0.0f;
    #pragma unroll
    for (int u = 0; u < UNROLL; ++u) {
        int i = base + u * 256;
        int pair = i / 15;                 // magic-mul
        int k = i - pair * 15;

        // neighbor gates (t4 of the row this lane's k==2/k==9 slot belongs to)
        float gx = __shfl_up(vt[u].x, 1, 64);
        float gz = __shfl_up(vt[u].z, 1, 64);
        if (lane == 0) {                   // rare fallback: previous i is in
            if (k == 2) gx = ts[pair * 60 + 4];    // another wave
            if (k == 9) gz = ts[pair * 60 + 34];
        }

        float d1 = vp[u].x - vt[u].x;      // k==1 term (even-row conf ch4)
        float d2 = vp[u].y - vt[u].y;      // k==2 term (even-row conf ch9)
        float d8 = vp[u].z - vt[u].z;      // k==8 term (odd-row conf ch4)
        float d9 = vp[u].w - vt[u].w;      // k==9 term (odd-row conf ch9)

        float c1 = (!(vt[u].x > 0.0f)) ? d1 * d1 : 0.0f;
        float c2 = (!(gx      > 0.0f)) ? d2 * d2 : 0.0f;
        float c8 = (!(vt[u].z > 0.0f)) ? d8 * d8 : 0.0f;
        float c9 = (!(gz      > 0.0f)) ? d9 * d9 : 0.0f;

        float contrib = (k == 1) ? c1 : (k == 2) ? c2 : (k == 8) ? c8
                      : (k == 9) ? c9 : 0.0f;
        acc += contrib;
    }

    // wave reduce -> cross-wave LDS -> one partial per block (no atomics)
    #pragma unroll
    for (int off = 32; off > 0; off >>= 1)
        acc += __shfl_down(acc, off, 64);
    __shared__ float s[4];
    int wid = tid >> 6;
    if (lane == 0) s[wid] = acc;
    __syncthreads();
    if (tid == 0)
        partials[blockIdx.x] = s[0] + s[1] + s[2] + s[3];
}

// ---------------------------------------------------------------------------
// Per-row "selected" bbox loss — faithful port of the reference including its
// bugs: x2y2 built from the already-transformed xy; lambda_coord only on the
// x / sqrt(w) terms; selected loss sums l1+l2+l3+IoU; argmax keeps first max.
// ---------------------------------------------------------------------------
__device__ inline float sel_loss(const float* __restrict__ p,
                                 const float* __restrict__ t, int row) {
    const float invS = 1.0f / 7.0f;
    int b0 = row * NCH;
    float tot0 = 0.f, tot1 = 0.f, iou0 = 0.f, iou1 = 0.f;
    #pragma unroll
    for (int j = 0; j < 2; ++j) {
        int o = b0 + 5 * j;
        float px = p[o + 0], py = p[o + 1], pw = p[o + 2], ph = p[o + 3], pc = p[o + 4];
        float tx = t[o + 0], ty = t[o + 1], tw = t[o + 2], th = t[o + 3], tc = t[o + 4];
        float pxy0 = px * invS - 0.5f * pw;
        float pxy1 = py * invS - 0.5f * ph;
        float p2x  = pxy0 * invS + 0.5f * pw;
        float p2y  = pxy1 * invS + 0.5f * ph;
        float txy0 = tx * invS - 0.5f * tw;
        float txy1 = ty * invS - 0.5f * th;
        float t2x  = txy0 * invS + 0.5f * tw;
        float t2y  = txy1 * invS + 0.5f * th;
        float d0 = txy0 - pxy0, d1 = txy1 - pxy1;
        float l1 = L_COORD * d0 * d0 + d1 * d1;
        float s0 = sqrtf(t2x) - sqrtf(p2x);
        float s1 = sqrtf(t2y) - sqrtf(p2y);
        float l2 = L_COORD * s0 * s0 + s1 * s1;
        float dc = tc - pc;
        float l3 = dc * dc;
        float ltx = fmaxf(pxy0, txy0), lty = fmaxf(pxy1, txy1);
        float rbx = fminf(p2x, t2x),   rby = fminf(p2y, t2y);
        float wx  = fmaxf(rbx - ltx, 0.0f);
        float wy  = fmaxf(rby - lty, 0.0f);
        float inter  = wx * wy;
        float area_p = (p2x - pxy0) * (p2y - pxy1);
        float area_t = (t2x - txy0) * (t2y - txy1);
        float io = inter / (area_p + area_t - inter);
        float tt = l1 + l2 + l3 + io;
        if (j == 0) { iou0 = io; tot0 = tt; }
        else        { iou1 = io; tot1 = tt; }
    }
    return (iou1 > iou0) ? tot1 : tot0;   // argmax keeps FIRST max
}

// ---------------------------------------------------------------------------
// K2: ordered ballot-scan for the bbox loss + final combine. Single block;
// uniform early exit once 49 objects consumed (~1 chunk at 25% density).
// Also folds the NB noobj partials.
// ---------------------------------------------------------------------------
__global__ __launch_bounds__(256) void bbox_kernel(const float* __restrict__ p,
                                                   const float* __restrict__ t,
                                                   const float* __restrict__ partials,
                                                   float* __restrict__ out, int M) {
    __shared__ int   s_wcnt[4];
    __shared__ int   s_base;
    __shared__ float s_part[4];
    if (threadIdx.x == 0) s_base = 0;
    __syncthreads();

    float local = 0.0f;
    for (int start = 0; start < M; start += 256) {
        int row = start + (int)threadIdx.x;
        bool obj = false;
        if (row < M) obj = t[row * NCH + 4] > 0.0f;

        unsigned long long mask = __ballot(obj);
        int lane = threadIdx.x & 63;
        int wid  = threadIdx.x >> 6;
        if (lane == 0) s_wcnt[wid] = __popcll(mask);
        __syncthreads();

        int base = s_base;
        int off = 0;
        for (int w = 0; w < wid; ++w) off += s_wcnt[w];
        int rank = base + off + __popcll(mask & ((1ULL << lane) - 1ULL));
        if (obj && rank < RANK_LIMIT) local += sel_loss(p, t, row);
        __syncthreads();

        if (threadIdx.x == 0)
            s_base = base + s_wcnt[0] + s_wcnt[1] + s_wcnt[2] + s_wcnt[3];
        __syncthreads();
        if (s_base >= RANK_LIMIT) break;
    }

    for (int i = threadIdx.x; i < NB; i += 256)
        local += L_NOOBJ * partials[i];

    #pragma unroll
    for (int o = 32; o > 0; o >>= 1)
        local += __shfl_down(local, o, 64);
    int lane = threadIdx.x & 63;
    int wid  = threadIdx.x >> 6;
    if (lane == 0) s_part[wid] = local;
    __syncthreads();
    if (threadIdx.x == 0)
        out[0] = s_part[0] + s_part[1] + s_part[2] + s_part[3];
}

extern "C" void kernel_launch(void* const* d_in, const int* in_sizes, int n_in,
                              void* d_out, int out_size, void* d_ws, size_t ws_size,
                              hipStream_t stream) {
    const float* pred = (const float*)d_in[0];
    const float* targ = (const float*)d_in[1];
    float* out = (float*)d_out;
    float* partials = (float*)d_ws;      // NB floats; all written before read

    int M = in_sizes[0] / NCH;           // 802816 rows

    noobj_kernel<<<NB, 256, 0, stream>>>((const vfloat4*)pred, (const vfloat4*)targ,
                                         targ, partials);
    bbox_kernel<<<1, 256, 0, stream>>>(pred, targ, partials, out, M);
}